// Round 1
// baseline (375.964 us; speedup 1.0000x reference)
//
#include <hip/hip_runtime.h>
#include <float.h>

// out[o][c] = max_{k<8} features[rules[o*8+k]][c],  C=64 floats per row.
// 16 lanes per output site, each lane owns 4 channels (one float4).
// A gathered row = 16 lanes x 16B = 256B coalesced segment.

__global__ __launch_bounds__(256) void maxpool_gather_kernel(
    const float4* __restrict__ feat,   // [N_IN * 16] float4
    const int*    __restrict__ rules,  // [N_OUT * 8]
    float4*       __restrict__ out,    // [N_OUT * 16] float4
    int n_out)
{
    int gid  = blockIdx.x * blockDim.x + threadIdx.x;
    int o    = gid >> 4;        // output site
    int lane = gid & 15;        // which float4 of the 16 in the row
    if (o >= n_out) return;

    // Load the 8 rule indices (two int4 loads; redundant across the 16
    // lanes of this site but served by L1 broadcast).
    const int4* r4 = reinterpret_cast<const int4*>(rules + o * 8);
    int4 ra = r4[0];
    int4 rb = r4[1];

    long long i0 = (long long)ra.x * 16 + lane;
    long long i1 = (long long)ra.y * 16 + lane;
    long long i2 = (long long)ra.z * 16 + lane;
    long long i3 = (long long)ra.w * 16 + lane;
    long long i4 = (long long)rb.x * 16 + lane;
    long long i5 = (long long)rb.y * 16 + lane;
    long long i6 = (long long)rb.z * 16 + lane;
    long long i7 = (long long)rb.w * 16 + lane;

    // Issue all 8 gathers up front; compiler keeps them in flight (vmcnt).
    float4 v0 = feat[i0];
    float4 v1 = feat[i1];
    float4 v2 = feat[i2];
    float4 v3 = feat[i3];
    float4 v4 = feat[i4];
    float4 v5 = feat[i5];
    float4 v6 = feat[i6];
    float4 v7 = feat[i7];

    float4 m;
    m.x = fmaxf(fmaxf(fmaxf(v0.x, v1.x), fmaxf(v2.x, v3.x)),
                fmaxf(fmaxf(v4.x, v5.x), fmaxf(v6.x, v7.x)));
    m.y = fmaxf(fmaxf(fmaxf(v0.y, v1.y), fmaxf(v2.y, v3.y)),
                fmaxf(fmaxf(v4.y, v5.y), fmaxf(v6.y, v7.y)));
    m.z = fmaxf(fmaxf(fmaxf(v0.z, v1.z), fmaxf(v2.z, v3.z)),
                fmaxf(fmaxf(v4.z, v5.z), fmaxf(v6.z, v7.z)));
    m.w = fmaxf(fmaxf(fmaxf(v0.w, v1.w), fmaxf(v2.w, v3.w)),
                fmaxf(fmaxf(v4.w, v5.w), fmaxf(v6.w, v7.w)));

    out[(long long)o * 16 + lane] = m;
}

extern "C" void kernel_launch(void* const* d_in, const int* in_sizes, int n_in,
                              void* d_out, int out_size, void* d_ws, size_t ws_size,
                              hipStream_t stream) {
    const float4* feat  = (const float4*)d_in[0];   // features [1e6, 64] f32
    const int*    rules = (const int*)d_in[1];      // rules [250000, 8] i32
    float4*       out   = (float4*)d_out;           // [250000, 64] f32

    const int n_out = in_sizes[1] / 8;              // 250000
    const int total_threads = n_out * 16;
    const int block = 256;
    const int grid  = (total_threads + block - 1) / block;

    maxpool_gather_kernel<<<grid, block, 0, stream>>>(feat, rules, out, n_out);
}

// Round 3
// 373.075 us; speedup vs baseline: 1.0077x; 1.0077x over previous
//
#include <hip/hip_runtime.h>

// out[o][c] = max_{k<8} features[rules[o*8+k]][c],  C=64 floats per row.
// 16 lanes per output site, each lane owns one float4 (4 channels).
// A gathered row = 16 lanes x 16B = 256B coalesced segment.
//
// VGPR diet: feature offsets are 32-bit byte offsets (table is 256 MB,
// fits uint) against a uniform SGPR base -> global_load saddr form,
// 1 VGPR per address instead of a 64-bit pair. __launch_bounds__(256,8)
// pins 8 waves/SIMD for max memory-level parallelism.
// Streaming traffic (rules in, out out) is nontemporal so the 256 MB
// feature table keeps L3 to itself (reuse factor ~2.4x).
//
// NOTE: __builtin_nontemporal_* requires native clang vector types, not
// HIP_vector_type wrappers -> use ext_vector_type typedefs.

typedef int   v4i __attribute__((ext_vector_type(4)));
typedef float v4f __attribute__((ext_vector_type(4)));

__global__ __launch_bounds__(256, 8) void maxpool_gather_kernel(
    const char* __restrict__ feat_base,  // features, byte-addressed
    const int*  __restrict__ rules,      // [N_OUT * 8]
    v4f*        __restrict__ out,        // [N_OUT * 16] float4
    int n_out)
{
    int gid  = blockIdx.x * blockDim.x + threadIdx.x;
    int o    = gid >> 4;        // output site
    int lane = gid & 15;        // which float4 of the 16 in the row
    if (o >= n_out) return;

    // 8 rule indices: two 16B loads, same address across the 16 lanes of
    // this site (hardware broadcast). Nontemporal: rules are read once.
    const v4i* r4 = reinterpret_cast<const v4i*>(rules + o * 8);
    v4i ra = __builtin_nontemporal_load(r4);
    v4i rb = __builtin_nontemporal_load(r4 + 1);

    unsigned lb = (unsigned)(lane << 4);           // lane * 16 bytes
    unsigned b0 = (unsigned)ra.x * 256u + lb;
    unsigned b1 = (unsigned)ra.y * 256u + lb;
    unsigned b2 = (unsigned)ra.z * 256u + lb;
    unsigned b3 = (unsigned)ra.w * 256u + lb;
    unsigned b4 = (unsigned)rb.x * 256u + lb;
    unsigned b5 = (unsigned)rb.y * 256u + lb;
    unsigned b6 = (unsigned)rb.z * 256u + lb;
    unsigned b7 = (unsigned)rb.w * 256u + lb;

    // Issue all 8 gathers before any use: 8-deep MLP per thread.
    v4f v0 = *reinterpret_cast<const v4f*>(feat_base + b0);
    v4f v1 = *reinterpret_cast<const v4f*>(feat_base + b1);
    v4f v2 = *reinterpret_cast<const v4f*>(feat_base + b2);
    v4f v3 = *reinterpret_cast<const v4f*>(feat_base + b3);
    v4f v4 = *reinterpret_cast<const v4f*>(feat_base + b4);
    v4f v5 = *reinterpret_cast<const v4f*>(feat_base + b5);
    v4f v6 = *reinterpret_cast<const v4f*>(feat_base + b6);
    v4f v7 = *reinterpret_cast<const v4f*>(feat_base + b7);

    v4f m;
    m.x = fmaxf(fmaxf(fmaxf(v0.x, v1.x), fmaxf(v2.x, v3.x)),
                fmaxf(fmaxf(v4.x, v5.x), fmaxf(v6.x, v7.x)));
    m.y = fmaxf(fmaxf(fmaxf(v0.y, v1.y), fmaxf(v2.y, v3.y)),
                fmaxf(fmaxf(v4.y, v5.y), fmaxf(v6.y, v7.y)));
    m.z = fmaxf(fmaxf(fmaxf(v0.z, v1.z), fmaxf(v2.z, v3.z)),
                fmaxf(fmaxf(v4.z, v5.z), fmaxf(v6.z, v7.z)));
    m.w = fmaxf(fmaxf(fmaxf(v0.w, v1.w), fmaxf(v2.w, v3.w)),
                fmaxf(fmaxf(v4.w, v5.w), fmaxf(v6.w, v7.w)));

    // Output is written once, never re-read: nontemporal keeps it out of L3.
    __builtin_nontemporal_store(m, &out[(long long)o * 16 + lane]);
}

extern "C" void kernel_launch(void* const* d_in, const int* in_sizes, int n_in,
                              void* d_out, int out_size, void* d_ws, size_t ws_size,
                              hipStream_t stream) {
    const char* feat  = (const char*)d_in[0];   // features [1e6, 64] f32
    const int*  rules = (const int*)d_in[1];    // rules [250000, 8] i32
    v4f*        out   = (v4f*)d_out;            // [250000, 64] f32

    const int n_out = in_sizes[1] / 8;          // 250000
    const long long total_threads = (long long)n_out * 16;
    const int block = 256;
    const int grid  = (int)((total_threads + block - 1) / block);

    maxpool_gather_kernel<<<grid, block, 0, stream>>>(feat, rules, out, n_out);
}